// Round 1
// baseline (99.005 us; speedup 1.0000x reference)
//
#include <hip/hip_runtime.h>
#include <math.h>

static constexpr int TLEN  = 1024;   // signal length
static constexpr int NSAMP = 1022;   // N = T - M, M = 2
static constexpr int NSIG  = 128;    // 64 pred + 64 targ
static constexpr float RTHR = 0.2f;
static constexpr float EPSN = 1e-8f;

__device__ __forceinline__ float wave_sum_f(float v) {
#pragma unroll
  for (int off = 32; off > 0; off >>= 1) v += __shfl_down(v, off);
  return v;
}

__device__ __forceinline__ unsigned wave_sum_u(unsigned v) {
#pragma unroll
  for (int off = 32; off > 0; off >>= 1) v += __shfl_down(v, off);
  return v;
}

// One block per signal: two-pass mean/std(ddof=1), write normalized signal,
// zero this signal's match counters (ws is poisoned 0xAA before every call).
__global__ __launch_bounds__(256) void normalize_kernel(
    const float* __restrict__ pred, const float* __restrict__ targ,
    float* __restrict__ xn, unsigned* __restrict__ counters) {
  const int s = blockIdx.x;
  const float* x = (s < 64) ? (pred + s * TLEN) : (targ + (s - 64) * TLEN);
  const int t = threadIdx.x;

  float v[4];
  float sum = 0.f;
#pragma unroll
  for (int k = 0; k < 4; k++) { v[k] = x[t + 256 * k]; sum += v[k]; }

  __shared__ float red[4];
  float wsum = wave_sum_f(sum);
  if ((t & 63) == 0) red[t >> 6] = wsum;
  __syncthreads();
  const float mean = (red[0] + red[1] + red[2] + red[3]) / (float)TLEN;
  __syncthreads();

  float ssq = 0.f;
#pragma unroll
  for (int k = 0; k < 4; k++) { float d = v[k] - mean; ssq += d * d; }
  wsum = wave_sum_f(ssq);
  if ((t & 63) == 0) red[t >> 6] = wsum;
  __syncthreads();
  const float var = (red[0] + red[1] + red[2] + red[3]) / (float)(TLEN - 1);
  const float denom = sqrtf(var) + EPSN;   // std(ddof=1) + eps

#pragma unroll
  for (int k = 0; k < 4; k++)
    xn[s * TLEN + t + 256 * k] = (v[k] - mean) / denom;

  if (t == 0) { counters[2 * s] = 0u; counters[2 * s + 1] = 0u; }
}

// grid (4, NSIG): each block covers 256 rows of one signal's N x N pair space.
// Whole normalized signal lives in LDS; all lanes read the same sx[j+2] per
// iteration (broadcast, conflict-free). Rolling y0/y1/y2 registers -> one
// ds_read per j iteration, hidden under ~9 VALU ops.
__global__ __launch_bounds__(256) void count_kernel(
    const float* __restrict__ xn, unsigned* __restrict__ counters) {
  const int s = blockIdx.y;
  __shared__ float sx[TLEN];
  const float* x = xn + s * TLEN;
  for (int k = threadIdx.x; k < TLEN; k += 256) sx[k] = x[k];
  __syncthreads();

  const int i = blockIdx.x * 256 + threadIdx.x;
  unsigned cm = 0, cm1 = 0;
  if (i < NSAMP) {
    const float xi0 = sx[i], xi1 = sx[i + 1], xi2 = sx[i + 2];
    float y0 = sx[0], y1 = sx[1];
#pragma unroll 4
    for (int j = 0; j < NSAMP; j++) {
      const float y2 = sx[j + 2];
      const float m  = fmaxf(fabsf(xi0 - y0), fabsf(xi1 - y1));
      const float m1 = fmaxf(m, fabsf(xi2 - y2));
      cm  += (m  <= RTHR) ? 1u : 0u;
      cm1 += (m1 <= RTHR) ? 1u : 0u;
      y0 = y1; y1 = y2;
    }
  }
  cm  = wave_sum_u(cm);
  cm1 = wave_sum_u(cm1);
  if ((threadIdx.x & 63) == 0) {
    atomicAdd(&counters[2 * s], cm);
    atomicAdd(&counters[2 * s + 1], cm1);
  }
}

// One wave: 64 channels -> entropy(pred) vs entropy(targ) -> MSE scalar.
__global__ __launch_bounds__(64) void final_kernel(
    const unsigned* __restrict__ counters, float* __restrict__ out) {
  const int c = threadIdx.x;  // 0..63
  float ent[2];
#pragma unroll
  for (int p = 0; p < 2; p++) {
    const int s = c + p * 64;
    const unsigned cm  = counters[2 * s];
    const unsigned cm1 = counters[2 * s + 1];
    const float ratio = (float)cm1 / (float)(cm > 0u ? cm : 1u);
    const float e = -logf(fmaxf(ratio, 1e-30f));
    ent[p] = (cm > 0u && cm1 > 0u) ? e : 0.f;
  }
  const float d = ent[0] - ent[1];
  const float sq = wave_sum_f(d * d);
  if (c == 0) out[0] = sq / 64.f;
}

extern "C" void kernel_launch(void* const* d_in, const int* in_sizes, int n_in,
                              void* d_out, int out_size, void* d_ws, size_t ws_size,
                              hipStream_t stream) {
  const float* pred = (const float*)d_in[0];
  const float* targ = (const float*)d_in[1];
  float* xn = (float*)d_ws;                                   // 128*1024 f32 = 512 KB
  unsigned* counters = (unsigned*)((char*)d_ws + (size_t)NSIG * TLEN * sizeof(float));

  normalize_kernel<<<NSIG, 256, 0, stream>>>(pred, targ, xn, counters);
  count_kernel<<<dim3(4, NSIG), 256, 0, stream>>>(xn, counters);
  final_kernel<<<1, 64, 0, stream>>>(counters, (float*)d_out);
}